// Round 11
// baseline (119.974 us; speedup 1.0000x reference)
//
#include <hip/hip_runtime.h>
#include <hip/hip_bf16.h>

typedef __attribute__((ext_vector_type(8))) short short8;      // 8 x bf16
typedef __attribute__((ext_vector_type(16))) float f32x16;     // 32x32 MFMA C/D
typedef __attribute__((ext_vector_type(4))) unsigned int uint4v;

#define NB 2
#define NS 2048
#define NH 16
#define ND 128
#define ROWS (NH * ND)       // 2048 floats between consecutive seq positions
#define KVB 32               // KV rows per step
#define NT (NS / KVB)        // 64 steps
#define QBLK 128             // 4 waves x 32 q-rows
#define NQB (NS / QBLK)      // 16
#define STEPB 8192           // one step image (K or V): 8 chunks x 64 lanes x 16B

__device__ __forceinline__ unsigned short f2bf(float f) {
  union { __hip_bfloat16 b; unsigned short u; } c;
  c.b = __float2bfloat16(f);  // RNE
  return c.u;
}

__device__ __forceinline__ short8 pack8(float4 a, float4 b, float s) {
  short8 r;
  r[0] = (short)f2bf(a.x * s); r[1] = (short)f2bf(a.y * s);
  r[2] = (short)f2bf(a.z * s); r[3] = (short)f2bf(a.w * s);
  r[4] = (short)f2bf(b.x * s); r[5] = (short)f2bf(b.y * s);
  r[6] = (short)f2bf(b.z * s); r[7] = (short)f2bf(b.w * s);
  return r;
}

__device__ __forceinline__ void pl32swap(unsigned int& a, unsigned int& b) {
  asm("v_permlane32_swap_b32 %0, %1" : "+v"(a), "+v"(b));
}

// ---------------- prepass: K/V -> MFMA-FRAGMENT-ORDERED per-step images ----------
// For each (bh, step t of 32 kv rows):
//  K image chunk (ks,l) @ (ks*64+l)*16 = bf16{ K[t*32 + (l&31)][ks*16 + (l>>5)*8 + e] }
//    -> wave load at step ks is 64 lanes x contiguous 16B = 1KB (perfectly coalesced)
//  V image chunk (g,l), g=dt*2+ks2 @ (g*64+l)*16 =
//    bf16{ V^T[dt*32 + (l&31)][ks2*16 + (l>>5)*8 + e] }  (V^T[d][kv])
__global__ __launch_bounds__(256) void prepass_kv(
    const float* __restrict__ Kg, const float* __restrict__ Vg,
    char* __restrict__ Kimg, char* __restrict__ Vimg) {
  const int blk = blockIdx.x;          // bh*NT + t
  const int t = blk & (NT - 1);
  const int bh = blk >> 6;
  const int h = bh & (NH - 1);
  const int b = bh >> 4;
  const int tid = threadIdx.x;
  const int l = tid & 63;
  const int l31 = l & 31;
  const int hi2 = l >> 5;

  const size_t ibase = (size_t)b * NS * ROWS + (size_t)h * ND + (size_t)t * KVB * ROWS;
  const float* Kp = Kg + ibase;
  const float* Vp = Vg + ibase;
  char* Kt = Kimg + (size_t)blk * STEPB;
  char* Vt = Vimg + (size_t)blk * STEPB;

  // K chunks: 512 chunks over 256 threads (2 each)
#pragma unroll
  for (int i = 0; i < 2; ++i) {
    const int ks = (tid >> 6) + i * 4;
    const float* src = Kp + (size_t)l31 * ROWS + ks * 16 + hi2 * 8;
    float4 a = *reinterpret_cast<const float4*>(src);
    float4 d = *reinterpret_cast<const float4*>(src + 4);
    *reinterpret_cast<short8*>(Kt + (ks * 64 + l) * 16) = pack8(a, d, 1.0f);
  }

  // V: transpose 32 kv-rows x 128 d via fp32 LDS tile
  __shared__ float vt[KVB][129];
  {
    const int r = tid >> 3;            // 0..31
    const int c0 = (tid & 7) * 16;     // 16 floats per thread
#pragma unroll
    for (int j = 0; j < 4; ++j) {
      float4 x = *reinterpret_cast<const float4*>(Vp + (size_t)r * ROWS + c0 + j * 4);
      vt[r][c0 + j * 4 + 0] = x.x; vt[r][c0 + j * 4 + 1] = x.y;
      vt[r][c0 + j * 4 + 2] = x.z; vt[r][c0 + j * 4 + 3] = x.w;
    }
  }
  __syncthreads();
#pragma unroll
  for (int i = 0; i < 2; ++i) {
    const int g = (tid >> 6) + i * 4;  // 0..7 = dt*2+ks2
    const int d = (g >> 1) * 32 + l31;
    const int kb = (g & 1) * 16 + hi2 * 8;
    short8 o8;
#pragma unroll
    for (int e = 0; e < 8; ++e) o8[e] = (short)f2bf(vt[kb + e][d]);
    *reinterpret_cast<short8*>(Vt + (g * 64 + l) * 16) = o8;
  }
}

// ---------------- main: zero-LDS, zero-barrier, free-running waves ---------------
// K/V MFMA fragments loaded straight from L2 (frag-ordered images; 1KB/wave-load).
// K register-double-buffered one step ahead (L2 latency hides under QK+SM); V
// loaded at step start, consumed after SM. No __shared__, no __syncthreads, no
// manual waitcnt: compiler inserts precise vmcnt before first register use.
// S^T = mfma(A=K,B=Q); O^T = mfma(A=V^T,B=P^T), P^T in-register via permlane32_swap.
// No-max softmax; 1/sqrt(D)*log2e folded into Q.
__global__ __launch_bounds__(256, 2) void fattn_fwd(
    const float* __restrict__ Qg, const char* __restrict__ Kimg,
    const char* __restrict__ Vimg, float* __restrict__ Og) {
  const int tid = threadIdx.x;
  const int l = tid & 63;
  const int w = tid >> 6;
  const int l31 = l & 31;
  const int hi2 = l >> 5;

  // XCD swizzle (nwg=512, %8==0): 64 consecutive wg per XCD = 4 bh -> 4x2MB images
  // L2-resident; consecutive wg share one bh (L1/L2 reuse across the 4-wave blocks).
  const int orig = blockIdx.x;
  const int wg = (orig & 7) * 64 + (orig >> 3);
  const int qblk = wg & (NQB - 1);
  const int bh = wg >> 4;
  const int h = bh & (NH - 1);
  const int b = bh >> 4;

  const float* Qp = Qg + (size_t)b * NS * ROWS + (size_t)h * ND;
  float* Op = Og + (size_t)b * NS * ROWS + (size_t)h * ND;
  const char* Ki = Kimg + (size_t)bh * NT * STEPB;
  const char* Vi = Vimg + (size_t)bh * NT * STEPB;

  const float scale = 0.08838834764831845f * 1.4426950408889634f;  // 1/sqrt(D)*log2e

  const int qrow = qblk * QBLK + w * 32 + l31;
  short8 qf[8];
  {
    const float* qr = Qp + (size_t)qrow * ROWS + hi2 * 8;
#pragma unroll
    for (int ks = 0; ks < 8; ++ks) {
      float4 a = *reinterpret_cast<const float4*>(qr + ks * 16);
      float4 c = *reinterpret_cast<const float4*>(qr + ks * 16 + 4);
      qf[ks] = pack8(a, c, scale);
    }
  }

  const int lo16 = l * 16;             // the single per-lane voffset
  f32x16 o[4];
#pragma unroll
  for (int dt = 0; dt < 4; ++dt) o[dt] = 0.f;
  float l_acc = 0.f;

  // softmax one 32-kv accumulator -> 2 P^T B-frags (kv 0..15 / 16..31) + l
  auto sm = [&](const f32x16& acc, short8& f0, short8& f1) {
    f32x16 p;
#pragma unroll
    for (int r = 0; r < 16; ++r) p[r] = exp2f(acc[r]);
    float s01 = (p[0] + p[1]) + (p[2] + p[3]);
    float s23 = (p[4] + p[5]) + (p[6] + p[7]);
    float s45 = (p[8] + p[9]) + (p[10] + p[11]);
    float s67 = (p[12] + p[13]) + (p[14] + p[15]);
    l_acc += (s01 + s23) + (s45 + s67);
    unsigned int X[4];
#pragma unroll
    for (int j = 0; j < 4; ++j)
      X[j] = (unsigned int)f2bf(p[2 * j]) | ((unsigned int)f2bf(p[2 * j + 1]) << 16);
    pl32swap(X[0], X[2]);
    pl32swap(X[1], X[3]);
    uint4v u0 = {X[0], X[1], X[2], X[3]};
    f0 = __builtin_bit_cast(short8, u0);
    unsigned int Y[4];
#pragma unroll
    for (int j = 0; j < 4; ++j)
      Y[j] = (unsigned int)f2bf(p[8 + 2 * j]) | ((unsigned int)f2bf(p[8 + 2 * j + 1]) << 16);
    pl32swap(Y[0], Y[2]);
    pl32swap(Y[1], Y[3]);
    uint4v u1 = {Y[0], Y[1], Y[2], Y[3]};
    f1 = __builtin_bit_cast(short8, u1);
  };

  short8 kA[8], kB[8];
  {
    const char* kp = Ki;               // step 0 K frags
#pragma unroll
    for (int ks = 0; ks < 8; ++ks)
      kA[ks] = *reinterpret_cast<const short8*>(kp + lo16 + ks * 1024);
  }

#pragma unroll 1
  for (int t = 0; t < NT; t += 2) {
    // ---- step t: compute from kA, prefetch K(t+1) -> kB ----
    {
      const char* vp = Vi + (size_t)t * STEPB;
      short8 vv[8];
#pragma unroll
      for (int g = 0; g < 8; ++g)
        vv[g] = *reinterpret_cast<const short8*>(vp + lo16 + g * 1024);
      if (t + 1 < NT) {
        const char* kp = Ki + (size_t)(t + 1) * STEPB;
#pragma unroll
        for (int ks = 0; ks < 8; ++ks)
          kB[ks] = *reinterpret_cast<const short8*>(kp + lo16 + ks * 1024);
      }
      f32x16 acc = 0.f;
#pragma unroll
      for (int ks = 0; ks < 8; ++ks)
        acc = __builtin_amdgcn_mfma_f32_32x32x16_bf16(kA[ks], qf[ks], acc, 0, 0, 0);
      short8 f0, f1;
      sm(acc, f0, f1);
#pragma unroll
      for (int dt = 0; dt < 4; ++dt) {
        o[dt] = __builtin_amdgcn_mfma_f32_32x32x16_bf16(vv[dt * 2], f0, o[dt], 0, 0, 0);
        o[dt] = __builtin_amdgcn_mfma_f32_32x32x16_bf16(vv[dt * 2 + 1], f1, o[dt], 0, 0, 0);
      }
    }
    // ---- step t+1: compute from kB, prefetch K(t+2) -> kA ----
    {
      const char* vp = Vi + (size_t)(t + 1) * STEPB;
      short8 vv[8];
#pragma unroll
      for (int g = 0; g < 8; ++g)
        vv[g] = *reinterpret_cast<const short8*>(vp + lo16 + g * 1024);
      if (t + 2 < NT) {
        const char* kp = Ki + (size_t)(t + 2) * STEPB;
#pragma unroll
        for (int ks = 0; ks < 8; ++ks)
          kA[ks] = *reinterpret_cast<const short8*>(kp + lo16 + ks * 1024);
      }
      f32x16 acc = 0.f;
#pragma unroll
      for (int ks = 0; ks < 8; ++ks)
        acc = __builtin_amdgcn_mfma_f32_32x32x16_bf16(kB[ks], qf[ks], acc, 0, 0, 0);
      short8 f0, f1;
      sm(acc, f0, f1);
#pragma unroll
      for (int dt = 0; dt < 4; ++dt) {
        o[dt] = __builtin_amdgcn_mfma_f32_32x32x16_bf16(vv[dt * 2], f0, o[dt], 0, 0, 0);
        o[dt] = __builtin_amdgcn_mfma_f32_32x32x16_bf16(vv[dt * 2 + 1], f1, o[dt], 0, 0, 0);
      }
    }
  }

  // ---- epilogue: l = own + cross-half; normalize + store ----
  const float lt = l_acc + __shfl_xor(l_acc, 32);
  const float inv = 1.0f / lt;
  float* orow = Op + (size_t)qrow * ROWS;
#pragma unroll
  for (int dt = 0; dt < 4; ++dt) {
#pragma unroll
    for (int g = 0; g < 4; ++g) {
      float4 v;
      v.x = o[dt][g * 4 + 0] * inv;
      v.y = o[dt][g * 4 + 1] * inv;
      v.z = o[dt][g * 4 + 2] * inv;
      v.w = o[dt][g * 4 + 3] * inv;
      *reinterpret_cast<float4*>(orow + dt * 32 + g * 8 + hi2 * 4) = v;
    }
  }
}

extern "C" void kernel_launch(void* const* d_in, const int* in_sizes, int n_in,
                              void* d_out, int out_size, void* d_ws, size_t ws_size,
                              hipStream_t stream) {
  const float* q = (const float*)d_in[0];
  const float* k = (const float*)d_in[1];
  const float* v = (const float*)d_in[2];
  float* out = (float*)d_out;
  (void)in_sizes; (void)n_in; (void)out_size; (void)ws_size;
  char* Kimg = (char*)d_ws;                                  // 32bh*64t*8KB = 16.8MB
  char* Vimg = Kimg + (size_t)NB * NH * NT * STEPB;          // 16.8MB
  prepass_kv<<<dim3(NB * NH * NT), dim3(256), 0, stream>>>(k, v, Kimg, Vimg);
  fattn_fwd<<<dim3(NQB * NB * NH), dim3(256), 0, stream>>>(q, Kimg, Vimg, out);
}